// Round 5
// baseline (1297.198 us; speedup 1.0000x reference)
//
#include <hip/hip_runtime.h>
#include <math.h>

// Problem dims
#define NB 16
#define NP 196
#define NE 1024
#define ND 512
#define NEMB 512
#define NV 10000
#define NL 32
#define NT 31
#define NG 2048  // 4*D

#define NBLK 256   // cooperative grid == CU count (proven-safe); 4 pods x 64

// d_out float offsets (real outputs)
#define OFF_PRED    0
#define OFF_CAPS    4960000
#define OFF_DECLEN  4960512
#define OFF_ALPHAS  4960528
#define OFF_SORTIND 5057744

// d_out-aliased scratch (floats; all dead before fc GEMM overwrites pred region)
#define OFF_ATT1B   0         // ushort[3136*1024]          -> 1,605,632 floats
#define OFF_PREIHB  1605632   // ushort[496*2048]           ->   507,904 floats
#define OFF_ENCT    2113536   // ushort[16*1024*208]        -> 1,703,936 floats (end 3,817,472)

// Workspace offsets (float granularity)
#define WS_LEAF   64         // per-pod barrier state: pod p at WS_LEAF + p*320 (8 leaves x32 + root@256 + gen@288)
#define WS_H      2304       // [16][512] fp32  (coherent exchange)
#define WS_C      10496      // [16][512] fp32  (block-private to D owners)
#define WS_M1     18688      // [16][4096] fp32 (coherent): att2 | gateS | gates_h (also k_mean scratch)
#define WS_SCORES 84224      // [16][256] fp32 (coherent)
#define WS_AWEG   88320      // [16][1024] fp32 (coherent)
#define WS_HHIST  104704     // ushort[31*16*512] = 126,976 floats -> end 231,680

// dynamic LDS layout for k_scan (bytes)
//  att1p : 13*1024 bf16                  = 26624   [0, 26624)
//  encp  : 64*210 bf16                   = 26880   [26624, 53504)
//  uni   : hs 4*640 f32 (10240) UNION ags 4*1280 f32 (20480)  [53504, 73984)
//  scratch: 2176 f32                     =  8704   [73984, 82688)
#define SMEM_BYTES 82688

__device__ __forceinline__ float sigf(float x){ return 1.0f/(1.0f+expf(-x)); }
__device__ __forceinline__ unsigned short bf16rne(float x){
  unsigned u = __float_as_uint(x);
  unsigned r = (u + 0x7fffu + ((u>>16)&1u)) >> 16;
  return (unsigned short)r;
}
__device__ __forceinline__ float bf2f(unsigned short h){ return __uint_as_float(((unsigned)h)<<16); }
__device__ __forceinline__ void u2f2(unsigned u, float&a, float&b){
  a = __uint_as_float(u<<16); b = __uint_as_float(u & 0xffff0000u);
}
// coherence-point (agent-scope) data exchange: bypasses non-coherent L2, NO cache invalidation
__device__ __forceinline__ void cstore(float* p, float v){
  __hip_atomic_store(p, v, __ATOMIC_RELAXED, __HIP_MEMORY_SCOPE_AGENT);
}
__device__ __forceinline__ float cload(const float* p){
  return __hip_atomic_load(p, __ATOMIC_RELAXED, __HIP_MEMORY_SCOPE_AGENT);
}
__device__ __forceinline__ float2 cload2(const float* p){
  unsigned long long u = __hip_atomic_load((const unsigned long long*)p, __ATOMIC_RELAXED, __HIP_MEMORY_SCOPE_AGENT);
  float2 r; r.x = __uint_as_float((unsigned)u); r.y = __uint_as_float((unsigned)(u>>32));
  return r;
}

// ---------------- sort + small outputs + barrier init ----------------
__global__ void k_sort(const int* __restrict__ caplen, const int* __restrict__ caps,
                       int* __restrict__ wsi, float* __restrict__ out){
  __shared__ int sidx[NB];
  int tid = threadIdx.x;
  if (tid == 0){
    int len[NB], idx[NB];
    for (int i=0;i<NB;i++){ len[i]=caplen[i]; idx[i]=i; }
    for (int i=1;i<NB;i++){
      int key=idx[i]; int kl=len[key]; int j=i-1;
      while (j>=0 && len[idx[j]]<kl){ idx[j+1]=idx[j]; j--; }
      idx[j+1]=key;
    }
    for (int b=0;b<NB;b++){
      sidx[b]=idx[b];
      wsi[b]=idx[b];
      int dl = len[idx[b]]-1;
      wsi[NB+b]=dl;
      out[OFF_DECLEN+b]=(float)dl;
      out[OFF_SORTIND+b]=(float)idx[b];
    }
  }
  __syncthreads();
  // zero barrier state [WS_LEAF, 2304)
  for (int x = tid; x < 2304-64; x += 64) ((unsigned*)wsi)[WS_LEAF + x] = 0u;
  for (int x=tid; x<NB*NL; x+=blockDim.x){
    int b = x>>5, l = x&31;
    out[OFF_CAPS + x] = (float)caps[sidx[b]*NL + l];
  }
}

// ---------------- mean over P (scratch in WS_M1 region) ----------------
__global__ __launch_bounds__(256) void k_mean(const float* __restrict__ enc,
                                              const int* __restrict__ wsi,
                                              float* __restrict__ wsf){
  int gid = blockIdx.x*256 + threadIdx.x;   // 16384 = 16*1024
  int b = gid>>10, e = gid&1023;
  int ob = wsi[b];
  const float* p = enc + (size_t)ob*NP*NE + e;
  float s = 0.f;
  for (int i=0;i<NP;i++) s += p[(size_t)i*NE];
  wsf[WS_M1 + b*NE + e] = s*(1.0f/196.0f);
}

// ---------------- h0/c0 init ----------------
__global__ __launch_bounds__(256) void k_init(const float* __restrict__ ihW, const float* __restrict__ ihb,
                                              const float* __restrict__ icW, const float* __restrict__ icb,
                                              float* __restrict__ wsf){
  int gid = blockIdx.x*256 + threadIdx.x;   // 16384
  int b = gid>>10, x = gid&1023;
  int d = x&511, which = x>>9;
  const float* W = which ? icW : ihW;
  const float* mp = wsf + WS_M1 + b*NE;
  float s = which ? icb[d] : ihb[d];
  for (int e=0;e<NE;e++) s = fmaf(mp[e], W[(size_t)e*ND + d], s);
  wsf[(which?WS_C:WS_H) + b*ND + d] = s;
}

// ---------------- enc transpose to bf16: encT[b][e][p], p padded to 208 ----------------
__global__ __launch_bounds__(256) void k_trans(const float* __restrict__ enc,
                                               const int* __restrict__ wsi,
                                               unsigned short* __restrict__ encT){
  __shared__ float tile[196*65];
  const int tid = threadIdx.x;
  const int b = blockIdx.x >> 4, et = blockIdx.x & 15;
  const int e0 = et*64;
  const int ob = wsi[b];
  for (int idx = tid; idx < 196*16; idx += 256){
    int p = idx >> 4, q = idx & 15;
    float4 v = *(const float4*)(enc + (size_t)ob*NP*NE + (size_t)p*NE + e0 + q*4);
    tile[p*65 + q*4+0] = v.x; tile[p*65 + q*4+1] = v.y;
    tile[p*65 + q*4+2] = v.z; tile[p*65 + q*4+3] = v.w;
  }
  __syncthreads();
  for (int idx = tid; idx < 64*52; idx += 256){
    int el = idx/52, c = idx%52;
    ushort4 o;
    int p = c*4;
    o.x = (p+0<196) ? bf16rne(tile[(p+0)*65 + el]) : (unsigned short)0;
    o.y = (p+1<196) ? bf16rne(tile[(p+1)*65 + el]) : (unsigned short)0;
    o.z = (p+2<196) ? bf16rne(tile[(p+2)*65 + el]) : (unsigned short)0;
    o.w = (p+3<196) ? bf16rne(tile[(p+3)*65 + el]) : (unsigned short)0;
    *(ushort4*)(encT + ((size_t)(b*1024 + e0 + el))*208 + c*4) = o;
  }
}

// ---------------- generic tiled fp32 GEMM 64x64 (bias2, mode1) — preih only ----------------
__global__ __launch_bounds__(256) void k_gemm(const void* __restrict__ Abase,
                                              const float* __restrict__ Bmat,
                                              const float* __restrict__ bias1,
                                              const float* __restrict__ bias2,
                                              void* __restrict__ outv,
                                              int M, int N, int K, int mode,
                                              int abf16, int obf16,
                                              const int* __restrict__ wsi,
                                              const int* __restrict__ caps){
  __shared__ float As[16*64];
  __shared__ float Bs[16*64];
  int tid = threadIdx.x;
  int n0 = blockIdx.x*64, m0 = blockIdx.y*64;
  int tx = tid&15, ty = tid>>4;
  float acc[4][4] = {};
  int r = tid>>2, kq = tid&3;
  int kk = tid>>4, nq = tid&15;
  int row = m0 + r;
  const float* arow = nullptr;
  const unsigned short* arowu = nullptr;
  if (row < M){
    if (mode==0){ int b=row/196, p=row%196; arow = (const float*)Abase + (size_t)(wsi[b]*196 + p)*NE; }
    else if (mode==1){ int t=row>>4, b=row&15; int cap = caps[wsi[b]*NL + t]; arow = (const float*)Abase + (size_t)cap*NEMB; }
    else {
      if (abf16) arowu = (const unsigned short*)Abase + (size_t)row*K;
      else       arow  = (const float*)Abase + (size_t)row*K;
    }
  }
  int ktiles = K>>4;
  for (int kt=0; kt<ktiles; kt++){
    int k0 = kt<<4;
    float4 av = make_float4(0.f,0.f,0.f,0.f);
    if (arow) av = *(const float4*)(arow + k0 + kq*4);
    else if (arowu){
      ushort4 t = *(const ushort4*)(arowu + k0 + kq*4);
      av.x = bf2f(t.x); av.y = bf2f(t.y); av.z = bf2f(t.z); av.w = bf2f(t.w);
    }
    As[(kq*4+0)*64 + r] = av.x;
    As[(kq*4+1)*64 + r] = av.y;
    As[(kq*4+2)*64 + r] = av.z;
    As[(kq*4+3)*64 + r] = av.w;
    int ncol = n0 + nq*4;
    const float* bp = Bmat + (size_t)(k0+kk)*N + ncol;
    float4 bv;
    if (ncol+3 < N) bv = *(const float4*)bp;
    else {
      bv.x = (ncol+0<N)?bp[0]:0.f; bv.y = (ncol+1<N)?bp[1]:0.f;
      bv.z = (ncol+2<N)?bp[2]:0.f; bv.w = (ncol+3<N)?bp[3]:0.f;
    }
    *((float4*)&Bs[kk*64 + nq*4]) = bv;
    __syncthreads();
    #pragma unroll
    for (int k=0;k<16;k++){
      const float4 a = *(const float4*)(&As[k*64 + ty*4]);
      const float4 b = *(const float4*)(&Bs[k*64 + tx*4]);
      float ar[4] = {a.x,a.y,a.z,a.w};
      float br[4] = {b.x,b.y,b.z,b.w};
      #pragma unroll
      for (int i=0;i<4;i++)
        #pragma unroll
        for (int j=0;j<4;j++)
          acc[i][j] = fmaf(ar[i], br[j], acc[i][j]);
    }
    __syncthreads();
  }
  #pragma unroll
  for (int i=0;i<4;i++){
    int m = m0 + ty*4 + i;
    if (m >= M) continue;
    #pragma unroll
    for (int j=0;j<4;j++){
      int n = n0 + tx*4 + j;
      if (n >= N) continue;
      float v = acc[i][j] + bias1[n];
      if (bias2) v += bias2[n];
      if (obf16) ((unsigned short*)outv)[(size_t)m*N + n] = bf16rne(v);
      else       ((float*)outv)[(size_t)m*N + n] = v;
    }
  }
}

// ---------------- register-blocked fp32 GEMM 128x128, 8x8 acc — att1 + fc ----------------
// Same k-ascending accumulation order as k_gemm -> bitwise-identical results.
__global__ __launch_bounds__(256) void k_gemm2(const void* __restrict__ Abase,
                                               const float* __restrict__ Bmat,
                                               const float* __restrict__ bias1,
                                               void* __restrict__ outv,
                                               int M, int N, int K, int mode,
                                               int abf16, int obf16,
                                               const int* __restrict__ wsi){
  __shared__ float As[16*128];
  __shared__ float Bs[16*128];
  const int tid = threadIdx.x;
  const int n0 = blockIdx.x*128, m0 = blockIdx.y*128;
  const int tx = tid & 15, ty = tid >> 4;      // out: rows m0+ty*8.., cols n0+tx*8..
  float acc[8][8] = {};
  // A staging: r in [0,128), 2 threads per row, kq = (tid&1)*8
  const int r = tid >> 1, kq = (tid & 1)*8;
  const int row = m0 + r;
  const float* arow = nullptr;
  const unsigned short* arowu = nullptr;
  if (row < M){
    if (mode==0){ int b=row/196, p=row%196; arow = (const float*)Abase + (size_t)(wsi[b]*196 + p)*NE; }
    else {
      if (abf16) arowu = (const unsigned short*)Abase + (size_t)row*K;
      else       arow  = (const float*)Abase + (size_t)row*K;
    }
  }
  // B staging: kk in [0,16), nq*8 cols
  const int kk = tid >> 4, nq = tid & 15;
  const int ncol = n0 + nq*8;
  const int ktiles = K >> 4;
  for (int kt=0; kt<ktiles; kt++){
    const int k0 = kt << 4;
    float av[8];
    #pragma unroll
    for (int i=0;i<8;i++) av[i] = 0.f;
    if (arow){
      float4 x = *(const float4*)(arow + k0 + kq);
      float4 y = *(const float4*)(arow + k0 + kq + 4);
      av[0]=x.x; av[1]=x.y; av[2]=x.z; av[3]=x.w;
      av[4]=y.x; av[5]=y.y; av[6]=y.z; av[7]=y.w;
    } else if (arowu){
      ushort4 t0 = *(const ushort4*)(arowu + k0 + kq);
      ushort4 t1 = *(const ushort4*)(arowu + k0 + kq + 4);
      av[0]=bf2f(t0.x); av[1]=bf2f(t0.y); av[2]=bf2f(t0.z); av[3]=bf2f(t0.w);
      av[4]=bf2f(t1.x); av[5]=bf2f(t1.y); av[6]=bf2f(t1.z); av[7]=bf2f(t1.w);
    }
    #pragma unroll
    for (int i=0;i<8;i++) As[(kq+i)*128 + r] = av[i];
    const float* bp = Bmat + (size_t)(k0+kk)*N + ncol;
    float bv[8];
    if (ncol + 7 < N){
      float4 x = *(const float4*)(bp);
      float4 y = *(const float4*)(bp + 4);
      bv[0]=x.x; bv[1]=x.y; bv[2]=x.z; bv[3]=x.w;
      bv[4]=y.x; bv[5]=y.y; bv[6]=y.z; bv[7]=y.w;
    } else {
      #pragma unroll
      for (int i=0;i<8;i++) bv[i] = (ncol+i < N) ? bp[i] : 0.f;
    }
    #pragma unroll
    for (int i=0;i<8;i++) Bs[kk*128 + nq*8 + i] = bv[i];
    __syncthreads();
    #pragma unroll
    for (int k=0;k<16;k++){
      const float4 a0 = *(const float4*)(&As[k*128 + ty*8]);
      const float4 a1 = *(const float4*)(&As[k*128 + ty*8 + 4]);
      const float4 b0 = *(const float4*)(&Bs[k*128 + tx*8]);
      const float4 b1 = *(const float4*)(&Bs[k*128 + tx*8 + 4]);
      float ar[8] = {a0.x,a0.y,a0.z,a0.w,a1.x,a1.y,a1.z,a1.w};
      float br[8] = {b0.x,b0.y,b0.z,b0.w,b1.x,b1.y,b1.z,b1.w};
      #pragma unroll
      for (int i=0;i<8;i++)
        #pragma unroll
        for (int j=0;j<8;j++)
          acc[i][j] = fmaf(ar[i], br[j], acc[i][j]);
    }
    __syncthreads();
  }
  if (mode == 2){
    // fc: masked scatter out[b][t][n]
    float* out = (float*)outv;
    #pragma unroll
    for (int i=0;i<8;i++){
      int m = m0 + ty*8 + i;
      if (m >= M) continue;
      int b = m & 15, t = m >> 4;
      bool act = wsi[NB + b] > t;
      size_t obase = (size_t)b*NT*NV + (size_t)t*NV;
      #pragma unroll
      for (int j=0;j<8;j++){
        int n = n0 + tx*8 + j;
        if (n >= N) continue;
        out[obase + n] = act ? (acc[i][j] + bias1[n]) : 0.0f;
      }
    }
  } else {
    #pragma unroll
    for (int i=0;i<8;i++){
      int m = m0 + ty*8 + i;
      if (m >= M) continue;
      #pragma unroll
      for (int j=0;j<8;j++){
        int n = n0 + tx*8 + j;
        if (n >= N) continue;
        float v = acc[i][j] + bias1[n];
        if (obf16) ((unsigned short*)outv)[(size_t)m*N + n] = bf16rne(v);
        else       ((float*)outv)[(size_t)m*N + n] = v;
      }
    }
  }
}

// ---------------- persistent cooperative scan, 4 pods x 64 blocks x 512 threads ----------------
struct ScanParams {
  float* wsf;
  const int* wsi;
  const unsigned short* att1b;
  const unsigned short* preihb;
  const unsigned short* encT;
  const float* dec_att_W;
  const float* dec_att_b;
  const float* f_beta_W;
  const float* f_beta_b;
  const float* W_hh;
  const float* W_ih;
  const float* full_att_W;
  const float* full_att_b;
  float* out;
};

// FENCE-FREE pod-local barrier (64 blocks: 8 leaves x 8, root x 8).
__device__ __forceinline__ void podbar(unsigned* base, int bxl, unsigned target){
  __syncthreads();
  if (threadIdx.x == 0){
    unsigned* lf = base + (bxl & 7)*32;
    unsigned a = __hip_atomic_fetch_add(lf, 1u, __ATOMIC_RELEASE, __HIP_MEMORY_SCOPE_AGENT);
    if (a == 7u){
      __hip_atomic_store(lf, 0u, __ATOMIC_RELAXED, __HIP_MEMORY_SCOPE_AGENT);
      unsigned r = __hip_atomic_fetch_add(base + 256, 1u, __ATOMIC_RELEASE, __HIP_MEMORY_SCOPE_AGENT);
      if (r == 7u){
        __hip_atomic_store(base + 256, 0u, __ATOMIC_RELAXED, __HIP_MEMORY_SCOPE_AGENT);
        __hip_atomic_fetch_add(base + 288, 1u, __ATOMIC_RELEASE, __HIP_MEMORY_SCOPE_AGENT);
      }
    }
    while ((int)(__hip_atomic_load(base + 288, __ATOMIC_RELAXED, __HIP_MEMORY_SCOPE_AGENT) - target) < 0)
      __builtin_amdgcn_s_sleep(1);
  }
  __syncthreads();
  __asm__ volatile("" ::: "memory");
}

__global__ __launch_bounds__(512, 2) void k_scan(ScanParams P){
  extern __shared__ __align__(16) unsigned char smem[];
  unsigned short* att1p = (unsigned short*)smem;              // [13][1024] bf16
  unsigned short* encp  = (unsigned short*)(smem + 26624);    // [64][210] bf16
  float* uni     = (float*)(smem + 53504);                    // hs (4x640) / ags (4x1280) union
  float* scratch = (float*)(smem + 73984);                    // 2176 f32

  const int tid = threadIdx.x;
  const int bx = blockIdx.x;           // [0,256)
  const int pod = bx >> 6;             // 4 pods
  const int bxl = bx & 63;             // pod-local block id
  const int B0 = pod*4;                // pod owns batches [B0, B0+4)
  const int lane = tid & 63;
  const int wid = tid >> 6;            // [0,8)

  float* M1     = P.wsf + WS_M1;
  float* hws    = P.wsf + WS_H;
  float* cws    = P.wsf + WS_C;
  float* scores = P.wsf + WS_SCORES;
  float* aweg   = P.wsf + WS_AWEG;
  unsigned short* hhist_us = (unsigned short*)(P.wsf + WS_HHIST);
  unsigned* bbase = (unsigned*)(P.wsf) + WS_LEAF + pod*320;
  const int* declen = P.wsi + NB;
  unsigned target = 0;

  const float* Wih2 = P.W_ih + (size_t)512*NG;
  const float fab = P.full_att_b[0];

  // ---- Phase A ownership: pod block bxl owns M1 cols [bxl*64, bxl*64+64), 4 batches.
  const int kcA = tid >> 6, cA = tid & 63;
  int modeA; const float* WAp; int jbA, ldwA;
  if (bxl < 16)      { WAp = P.dec_att_W; jbA = bxl*64;       ldwA = 1024; modeA = 0; }
  else if (bxl < 32) { WAp = P.f_beta_W;  jbA = (bxl-16)*64;  ldwA = 1024; modeA = 1; }
  else               { WAp = P.W_hh;      jbA = (bxl-32)*64;  ldwA = 2048; modeA = 2; }
  float wA[64];
  #pragma unroll
  for (int i=0;i<64;i++) wA[i] = WAp[(size_t)(kcA*64+i)*ldwA + jbA + cA];

  // ---- Phase D ownership: pod block bxl owns d-slice [bxl*8, bxl*8+8) x 4 gates, 4 batches.
  const int kcD = tid >> 5, cD = tid & 31;
  const int jD = (cD>>3)*512 + bxl*8 + (cD&7);
  float wD[64];
  #pragma unroll
  for (int i=0;i<64;i++) wD[i] = Wih2[(size_t)(kcD*64+i)*NG + jD];

  // persistent full_att_W fragment in registers (lane-sliced)
  float faw[16];
  {
    const float* fw = P.full_att_W + lane*8;
    #pragma unroll
    for (int i=0;i<2;i++){
      float4 x = *(const float4*)(fw + i*512);
      float4 y = *(const float4*)(fw + i*512 + 4);
      faw[i*8+0]=x.x; faw[i*8+1]=x.y; faw[i*8+2]=x.z; faw[i*8+3]=x.w;
      faw[i*8+4]=y.x; faw[i*8+5]=y.y; faw[i*8+6]=y.z; faw[i*8+7]=y.w;
    }
  }

  // ---- one-time preload of persistent LDS (block-private bf16 slices) ----
  {
    const int b = bx >> 4, sub = bx & 15;
    const int p0 = sub*13;
    const int cnt = (sub==15) ? 1 : 13;
    const uint4* s4 = (const uint4*)(P.att1b + ((size_t)(b*196 + p0))*1024);
    uint4* d4 = (uint4*)att1p;
    for (int i = tid; i < cnt*128; i += 512) d4[i] = s4[i];
    const unsigned* es = (const unsigned*)P.encT + (((size_t)(b*1024 + sub*64))*208 >> 1);
    unsigned* ed = (unsigned*)encp;
    for (int i = tid; i < 64*104; i += 512){
      int el = i/104, c = i%104;
      ed[el*105 + c] = es[el*104 + c];
    }
  }
  __syncthreads();

  float pa[4];

  for (int tt=0; tt<NT; tt++){
    // ---- pod early-exit: all batches in pod done (declen sorted desc within pod)
    if (declen[B0] <= tt){
      if ((bxl & 15) == 0){
        int b = B0 + (bxl >> 4);
        for (int t2 = tt; t2 < NT; t2++)
          for (int p = tid; p < NP; p += 512)
            P.out[OFF_ALPHAS + (size_t)b*NT*NP + (size_t)t2*NP + p] = 0.f;
      }
      break;
    }

    // ---- preamble: load h(tt) for pod's 4 batches into LDS (20-word padded chunks)
    #pragma unroll
    for (int i=0;i<2;i++){
      int idx = tid + i*512;           // float2 units [0,1024)
      int b = idx >> 8, dp = (idx & 255)*2;
      float2 v = cload2(hws + (size_t)(B0+b)*ND + dp);
      int a = b*640 + (dp>>4)*20 + (dp&15);
      uni[a]   = v.x;
      uni[a+1] = v.y;
    }
    __syncthreads();

    // ---- Phase A: M1[B0+b][bxl*64+c] ; weights in regs, split-K (8 waves) LDS reduce
    {
      #pragma unroll
      for (int b=0;b<4;b++){
        float s = 0.f;
        #pragma unroll
        for (int cq=0;cq<4;cq++){
          const float4* hp = (const float4*)(uni + b*640 + kcA*80 + cq*20);
          float4 a0 = hp[0], a1 = hp[1], a2 = hp[2], a3 = hp[3];
          s = fmaf(a0.x,wA[cq*16+0],s);  s = fmaf(a0.y,wA[cq*16+1],s);  s = fmaf(a0.z,wA[cq*16+2],s);  s = fmaf(a0.w,wA[cq*16+3],s);
          s = fmaf(a1.x,wA[cq*16+4],s);  s = fmaf(a1.y,wA[cq*16+5],s);  s = fmaf(a1.z,wA[cq*16+6],s);  s = fmaf(a1.w,wA[cq*16+7],s);
          s = fmaf(a2.x,wA[cq*16+8],s);  s = fmaf(a2.y,wA[cq*16+9],s);  s = fmaf(a2.z,wA[cq*16+10],s); s = fmaf(a2.w,wA[cq*16+11],s);
          s = fmaf(a3.x,wA[cq*16+12],s); s = fmaf(a3.y,wA[cq*16+13],s); s = fmaf(a3.z,wA[cq*16+14],s); s = fmaf(a3.w,wA[cq*16+15],s);
        }
        pa[b] = s;
      }
      #pragma unroll
      for (int b=0;b<4;b++) scratch[kcA*256 + b*64 + cA] = pa[b];
      __syncthreads();
      if (tid < 256){
        float s = 0.f;
        #pragma unroll
        for (int w=0;w<8;w++) s += scratch[w*256 + tid];
        int b = tid >> 6, c = tid & 63;
        int jout = bxl*64 + c;
        float v;
        if (modeA==0)      v = s + P.dec_att_b[jout];
        else if (modeA==1) v = sigf(s + P.f_beta_b[jout-1024]);
        else               v = s;
        cstore(&M1[(size_t)(B0+b)*4096 + jout], v);
      }
    }
    podbar(bbase, bxl, ++target);

    // ---- Phase B: scores = relu(att1b + att2).faw + fab  (att1 rows from LDS)
    {
      const int b = B0 + (bxl >> 4), sidx = bxl & 15;
      if (declen[b] > tt){
        float a2r[16];
        {
          const float* m1b = M1 + (size_t)b*4096 + lane*8;
          #pragma unroll
          for (int i=0;i<2;i++){
            #pragma unroll
            for (int q=0;q<4;q++){
              float2 t = cload2(m1b + i*512 + q*2);
              a2r[i*8+q*2]   = t.x;
              a2r[i*8+q*2+1] = t.y;
            }
          }
        }
        const int p0 = sidx*13;
        const int cnt = (sidx==15) ? 1 : 13;
        for (int rr = wid; rr < cnt; rr += 8){
          int p = p0 + rr;
          const unsigned short* a1 = att1p + (size_t)rr*1024;
          float s = 0.f;
          #pragma unroll
          for (int i=0;i<2;i++){
            uint4 u = *(const uint4*)(a1 + i*512 + lane*8);
            float f0,f1,v;
            u2f2(u.x,f0,f1);
            v = f0 + a2r[i*8+0]; v = v>0.f?v:0.f; s = fmaf(v, faw[i*8+0], s);
            v = f1 + a2r[i*8+1]; v = v>0.f?v:0.f; s = fmaf(v, faw[i*8+1], s);
            u2f2(u.y,f0,f1);
            v = f0 + a2r[i*8+2]; v = v>0.f?v:0.f; s = fmaf(v, faw[i*8+2], s);
            v = f1 + a2r[i*8+3]; v = v>0.f?v:0.f; s = fmaf(v, faw[i*8+3], s);
            u2f2(u.z,f0,f1);
            v = f0 + a2r[i*8+4]; v = v>0.f?v:0.f; s = fmaf(v, faw[i*8+4], s);
            v = f1 + a2r[i*8+5]; v = v>0.f?v:0.f; s = fmaf(v, faw[i*8+5], s);
            u2f2(u.w,f0,f1);
            v = f0 + a2r[i*8+6]; v = v>0.f?v:0.f; s = fmaf(v, faw[i*8+6], s);
            v = f1 + a2r[i*8+7]; v = v>0.f?v:0.f; s = fmaf(v, faw[i*8+7], s);
          }
          #pragma unroll
          for (int off=32; off; off>>=1) s += __shfl_down(s, off, 64);
          if (lane == 0) cstore(&scores[b*256 + p], s + fab);
        }
      }
    }
    podbar(bbase, bxl, ++target);

    // ---- Phase C: redundant softmax + awe chunk (64 e) from LDS encp; aweg coherent
    {
      const int b = B0 + (bxl >> 4), ch = bxl & 15;
      if (declen[b] <= tt){
        if (ch == 0 && tid < 196)
          P.out[OFF_ALPHAS + (size_t)b*NT*NP + (size_t)tt*NP + tid] = 0.f;
      } else {
        float* sc   = scratch;            // 208
        float* red2 = scratch + 208;      // 256
        float* redp = scratch + 464;      // 8*68
        float v = (tid < 196) ? cload(&scores[b*256 + tid]) : -1e30f;
        if (tid < 208) sc[tid] = v;
        if (tid < 256) red2[tid] = v;
        __syncthreads();
        for (int s2=128; s2; s2>>=1){ if (tid < s2) red2[tid] = fmaxf(red2[tid], red2[tid+s2]); __syncthreads(); }
        const float mx = red2[0];
        __syncthreads();
        float ex = (tid < 196) ? expf(sc[tid] - mx) : 0.f;
        if (tid < 208) sc[tid] = ex;
        if (tid < 256) red2[tid] = ex;
        __syncthreads();
        for (int s2=128; s2; s2>>=1){ if (tid < s2) red2[tid] += red2[tid+s2]; __syncthreads(); }
        const float inv = 1.f / red2[0];
        __syncthreads();
        if (tid < 208) sc[tid] *= inv;    // alpha, zero-padded to 208
        __syncthreads();
        const int el = tid & 63, pp = tid >> 6;
        const unsigned* erowL = ((const unsigned*)encp) + el*105 + pp*13;
        float part = 0.f;
        #pragma unroll
        for (int i=0;i<13;i++){
          unsigned u = erowL[i];
          float f0,f1; u2f2(u,f0,f1);
          part = fmaf(f0, sc[pp*26 + 2*i],     part);
          part = fmaf(f1, sc[pp*26 + 2*i + 1], part);
        }
        redp[pp*68 + el] = part;
        __syncthreads();
        if (tid < 64){
          float aw = 0.f;
          #pragma unroll
          for (int q=0;q<8;q++) aw += redp[q*68 + tid];
          int e2 = ch*64 + tid;
          cstore(&aweg[b*1024 + e2], cload(&M1[(size_t)b*4096 + 1024 + e2]) + aw);
        }
        if (ch == 0 && tid < 196){
          P.out[OFF_ALPHAS + (size_t)b*NT*NP + (size_t)tt*NP + tid] = sc[tid];
        }
        __syncthreads();
      }
    }
    podbar(bbase, bxl, ++target);

    // ---- Phase D: gates for d-slice [bxl*8, bxl*8+8) x 4 gates, pod's 4 batches
    {
      #pragma unroll
      for (int i=0;i<4;i++){
        int idx = tid + i*512;          // float2 units [0,2048)
        int b = idx >> 9, ep = (idx & 511)*2;
        float2 v = cload2(aweg + (size_t)(B0+b)*1024 + ep);
        int a = b*1280 + (ep>>4)*20 + (ep&15);
        uni[a]   = v.x;
        uni[a+1] = v.y;
      }
      __syncthreads();
      #pragma unroll
      for (int b=0;b<4;b++){
        float s = 0.f;
        #pragma unroll
        for (int cq=0;cq<4;cq++){
          const float4* ap = (const float4*)(uni + b*1280 + kcD*80 + cq*20);
          float4 a0 = ap[0], a1 = ap[1], a2 = ap[2], a3 = ap[3];
          s = fmaf(a0.x,wD[cq*16+0],s);  s = fmaf(a0.y,wD[cq*16+1],s);  s = fmaf(a0.z,wD[cq*16+2],s);  s = fmaf(a0.w,wD[cq*16+3],s);
          s = fmaf(a1.x,wD[cq*16+4],s);  s = fmaf(a1.y,wD[cq*16+5],s);  s = fmaf(a1.z,wD[cq*16+6],s);  s = fmaf(a1.w,wD[cq*16+7],s);
          s = fmaf(a2.x,wD[cq*16+8],s);  s = fmaf(a2.y,wD[cq*16+9],s);  s = fmaf(a2.z,wD[cq*16+10],s); s = fmaf(a2.w,wD[cq*16+11],s);
          s = fmaf(a3.x,wD[cq*16+12],s); s = fmaf(a3.y,wD[cq*16+13],s); s = fmaf(a3.z,wD[cq*16+14],s); s = fmaf(a3.w,wD[cq*16+15],s);
        }
        pa[b] = s;
      }
      #pragma unroll
      for (int b=0;b<4;b++) scratch[kcD*128 + b*32 + cD] = pa[b];
      __syncthreads();
      float* gl = scratch + 2048;       // 128
      if (tid < 128){
        float s = 0.f;
        #pragma unroll
        for (int w=0;w<16;w++) s += scratch[w*128 + tid];
        int c = tid & 31, b = tid >> 5;
        int j = (c>>3)*512 + bxl*8 + (c&7);
        int B = B0 + b;
        float gv = s + bf2f(P.preihb[(size_t)(tt*NB + B)*NG + j]) + cload(&M1[(size_t)B*4096 + 2048 + j]);
        gl[b*32 + c] = gv;              // c = g*8+dq
      }
      __syncthreads();
      if (tid < 32){
        const int b = tid >> 3, dq = tid & 7;
        const int B = B0 + b, d = bxl*8 + dq;
        const float gI = gl[b*32 + 0  + dq];
        const float gF = gl[b*32 + 8  + dq];
        const float gG = gl[b*32 + 16 + dq];
        const float gO = gl[b*32 + 24 + dq];
        const float co = cws[(size_t)B*ND + d];  // block-private (same owner every step)
        const float cn = sigf(gF)*co + sigf(gI)*tanhf(gG);
        const float hn = sigf(gO)*tanhf(cn);
        hhist_us[((size_t)tt*NB + B)*ND + d] = bf16rne(hn);
        if (declen[B] > tt){
          cstore(&hws[(size_t)B*ND + d], hn);    // broadcast h coherently
          cws[(size_t)B*ND + d] = cn;
        }
      }
      __syncthreads();
    }
    podbar(bbase, bxl, ++target);
  }
}

extern "C" void kernel_launch(void* const* d_in, const int* in_sizes, int n_in,
                              void* d_out, int out_size, void* d_ws, size_t ws_size,
                              hipStream_t stream) {
  const float* encoder_out = (const float*)d_in[0];
  const float* enc_att_W   = (const float*)d_in[1];
  const float* enc_att_b   = (const float*)d_in[2];
  const float* dec_att_W   = (const float*)d_in[3];
  const float* dec_att_b   = (const float*)d_in[4];
  const float* full_att_W  = (const float*)d_in[5];
  const float* full_att_b  = (const float*)d_in[6];
  const float* emb         = (const float*)d_in[7];
  const float* W_ih        = (const float*)d_in[8];
  const float* b_ih        = (const float*)d_in[9];
  const float* W_hh        = (const float*)d_in[10];
  const float* b_hh        = (const float*)d_in[11];
  const float* init_h_W    = (const float*)d_in[12];
  const float* init_h_b    = (const float*)d_in[13];
  const float* init_c_W    = (const float*)d_in[14];
  const float* init_c_b    = (const float*)d_in[15];
  const float* f_beta_W    = (const float*)d_in[16];
  const float* f_beta_b    = (const float*)d_in[17];
  const float* fc_W        = (const float*)d_in[18];
  const float* fc_b        = (const float*)d_in[19];
  const int*   caps        = (const int*)d_in[20];
  const int*   caplen      = (const int*)d_in[21];
  (void)in_sizes; (void)n_in; (void)out_size; (void)ws_size;

  float* out = (float*)d_out;
  float* wsf = (float*)d_ws;
  int*   wsi = (int*)d_ws;
  unsigned short* att1b  = (unsigned short*)(out + OFF_ATT1B);
  unsigned short* preihb = (unsigned short*)(out + OFF_PREIHB);
  unsigned short* encT   = (unsigned short*)(out + OFF_ENCT);

  hipFuncSetAttribute((const void*)k_scan, hipFuncAttributeMaxDynamicSharedMemorySize, SMEM_BYTES);

  hipLaunchKernelGGL(k_sort, dim3(1), dim3(64), 0, stream, caplen, caps, wsi, out);
  hipLaunchKernelGGL(k_mean, dim3(64), dim3(256), 0, stream, encoder_out, wsi, wsf);
  hipLaunchKernelGGL(k_init, dim3(64), dim3(256), 0, stream, init_h_W, init_h_b, init_c_W, init_c_b, wsf);
  hipLaunchKernelGGL(k_trans, dim3(256), dim3(256), 0, stream, encoder_out, wsi, encT);
  // att1 (bf16 out) : M=3136, N=1024, K=1024  (128x128 tiles)
  hipLaunchKernelGGL(k_gemm2, dim3(8,25), dim3(256), 0, stream,
                     (const void*)encoder_out, enc_att_W, enc_att_b,
                     (void*)att1b, 3136, 1024, 1024, 0, 0, 1, wsi);
  // pre_ih (bf16 out) : M=496, N=2048, K=512  (64x64 tiles fit this shape better)
  hipLaunchKernelGGL(k_gemm, dim3(32,8), dim3(256), 0, stream,
                     (const void*)emb, W_ih, b_ih, b_hh,
                     (void*)preihb, 496, 2048, 512, 1, 0, 1, wsi, caps);

  ScanParams sp;
  sp.wsf = wsf; sp.wsi = wsi;
  sp.att1b = att1b; sp.preihb = preihb; sp.encT = encT;
  sp.dec_att_W = dec_att_W; sp.dec_att_b = dec_att_b;
  sp.f_beta_W = f_beta_W; sp.f_beta_b = f_beta_b;
  sp.W_hh = W_hh; sp.W_ih = W_ih;
  sp.full_att_W = full_att_W; sp.full_att_b = full_att_b;
  sp.out = out;
  void* args[] = { &sp };
  hipLaunchCooperativeKernel((void*)k_scan, dim3(NBLK), dim3(512), args, SMEM_BYTES, stream);

  // predictions = hhist(bf16) @ fc_W + fc_b (masked) : M=496, N=10000, K=512  (128x128 tiles)
  hipLaunchKernelGGL(k_gemm2, dim3(79,4), dim3(256), 0, stream,
                     (const void*)(wsf + WS_HHIST), fc_W, fc_b,
                     (void*)out, 496, 10000, 512, 2, 1, 0, wsi);
}

// Round 6
// 1192.664 us; speedup vs baseline: 1.0876x; 1.0876x over previous
//
#include <hip/hip_runtime.h>
#include <math.h>

// Problem dims
#define NB 16
#define NP 196
#define NE 1024
#define ND 512
#define NEMB 512
#define NV 10000
#define NL 32
#define NT 31
#define NG 2048  // 4*D

#define NBLK 256   // cooperative grid == CU count (proven-safe); 4 pods x 64

// d_out float offsets (real outputs)
#define OFF_PRED    0
#define OFF_CAPS    4960000
#define OFF_DECLEN  4960512
#define OFF_ALPHAS  4960528
#define OFF_SORTIND 5057744

// d_out-aliased scratch (floats; all dead before fc GEMM overwrites pred region)
#define OFF_ATT1B   0         // ushort[3136*1024]          -> 1,605,632 floats
#define OFF_PREIHB  1605632   // ushort[496*2048]           ->   507,904 floats
#define OFF_ENCT    2113536   // ushort[16*1024*208]        -> 1,703,936 floats (end 3,817,472)

// Workspace offsets (float granularity)
// wsi[0..15] sorted idx, wsi[16..31] declen, wsi[32..39] fc m-block any-active flags
#define WS_LEAF   64         // per-pod barrier state: pod p at WS_LEAF + p*320 (8 leaves x32 + root@256 + gen@288)
#define WS_H      2304       // [16][512] fp32  (coherent exchange)
#define WS_C      10496      // [16][512] fp32  (block-private to D owners)
#define WS_M1     18688      // [16][4096] fp32 (coherent): att2 | gateS | gates_h (also k_mean scratch)
#define WS_SCORES 84224      // [16][256] fp32 (coherent)
#define WS_AWEG   88320      // [16][1024] fp32 (coherent)
#define WS_HHIST  104704     // ushort[31*16*512] = 126,976 floats -> end 231,680

// dynamic LDS layout for k_scan (bytes)
//  att1p : 13*1024 bf16                  = 26624   [0, 26624)
//  encp  : 64*210 bf16                   = 26880   [26624, 53504)
//  uni   : hs 4*640 f32 (10240) UNION ags 4*1280 f32 (20480)  [53504, 73984)
//  scratch: 2176 f32                     =  8704   [73984, 82688)
#define SMEM_BYTES 82688

__device__ __forceinline__ float sigf(float x){ return 1.0f/(1.0f+expf(-x)); }
__device__ __forceinline__ unsigned short bf16rne(float x){
  unsigned u = __float_as_uint(x);
  unsigned r = (u + 0x7fffu + ((u>>16)&1u)) >> 16;
  return (unsigned short)r;
}
__device__ __forceinline__ float bf2f(unsigned short h){ return __uint_as_float(((unsigned)h)<<16); }
__device__ __forceinline__ void u2f2(unsigned u, float&a, float&b){
  a = __uint_as_float(u<<16); b = __uint_as_float(u & 0xffff0000u);
}
// coherence-point (agent-scope) data exchange: bypasses non-coherent L2, NO cache invalidation
__device__ __forceinline__ void cstore(float* p, float v){
  __hip_atomic_store(p, v, __ATOMIC_RELAXED, __HIP_MEMORY_SCOPE_AGENT);
}
__device__ __forceinline__ float cload(const float* p){
  return __hip_atomic_load(p, __ATOMIC_RELAXED, __HIP_MEMORY_SCOPE_AGENT);
}
__device__ __forceinline__ float2 cload2(const float* p){
  unsigned long long u = __hip_atomic_load((const unsigned long long*)p, __ATOMIC_RELAXED, __HIP_MEMORY_SCOPE_AGENT);
  float2 r; r.x = __uint_as_float((unsigned)u); r.y = __uint_as_float((unsigned)(u>>32));
  return r;
}

// ---------------- sort + small outputs + barrier init ----------------
__global__ void k_sort(const int* __restrict__ caplen, const int* __restrict__ caps,
                       int* __restrict__ wsi, float* __restrict__ out){
  __shared__ int sidx[NB];
  int tid = threadIdx.x;
  if (tid == 0){
    int len[NB], idx[NB];
    for (int i=0;i<NB;i++){ len[i]=caplen[i]; idx[i]=i; }
    for (int i=1;i<NB;i++){
      int key=idx[i]; int kl=len[key]; int j=i-1;
      while (j>=0 && len[idx[j]]<kl){ idx[j+1]=idx[j]; j--; }
      idx[j+1]=key;
    }
    int dl[NB];
    for (int b=0;b<NB;b++){
      sidx[b]=idx[b];
      wsi[b]=idx[b];
      dl[b] = len[idx[b]]-1;
      wsi[NB+b]=dl[b];
      out[OFF_DECLEN+b]=(float)dl[b];
      out[OFF_SORTIND+b]=(float)idx[b];
    }
    // fc m-block any-active flags (fc row order m = b*31 + t)
    for (int mb=0; mb<8; mb++){
      int any = 0;
      for (int m=mb*64; m<mb*64+64 && m<NB*NT; m++){
        int b = m/NT, t = m - b*NT;
        if (t < dl[b]) any = 1;
      }
      wsi[32+mb] = any;
    }
  }
  __syncthreads();
  // zero barrier state [WS_LEAF, 2304)
  for (int x = tid; x < 2304-64; x += 64) ((unsigned*)wsi)[WS_LEAF + x] = 0u;
  for (int x=tid; x<NB*NL; x+=blockDim.x){
    int b = x>>5, l = x&31;
    out[OFF_CAPS + x] = (float)caps[sidx[b]*NL + l];
  }
}

// ---------------- mean over P (scratch in WS_M1 region) ----------------
__global__ __launch_bounds__(256) void k_mean(const float* __restrict__ enc,
                                              const int* __restrict__ wsi,
                                              float* __restrict__ wsf){
  int gid = blockIdx.x*256 + threadIdx.x;   // 16384 = 16*1024
  int b = gid>>10, e = gid&1023;
  int ob = wsi[b];
  const float* p = enc + (size_t)ob*NP*NE + e;
  float s = 0.f;
  for (int i=0;i<NP;i++) s += p[(size_t)i*NE];
  wsf[WS_M1 + b*NE + e] = s*(1.0f/196.0f);
}

// ---------------- h0/c0 init ----------------
__global__ __launch_bounds__(256) void k_init(const float* __restrict__ ihW, const float* __restrict__ ihb,
                                              const float* __restrict__ icW, const float* __restrict__ icb,
                                              float* __restrict__ wsf){
  int gid = blockIdx.x*256 + threadIdx.x;   // 16384
  int b = gid>>10, x = gid&1023;
  int d = x&511, which = x>>9;
  const float* W = which ? icW : ihW;
  const float* mp = wsf + WS_M1 + b*NE;
  float s = which ? icb[d] : ihb[d];
  for (int e=0;e<NE;e++) s = fmaf(mp[e], W[(size_t)e*ND + d], s);
  wsf[(which?WS_C:WS_H) + b*ND + d] = s;
}

// ---------------- enc transpose to bf16: encT[b][e][p], p padded to 208 ----------------
__global__ __launch_bounds__(256) void k_trans(const float* __restrict__ enc,
                                               const int* __restrict__ wsi,
                                               unsigned short* __restrict__ encT){
  __shared__ float tile[196*65];
  const int tid = threadIdx.x;
  const int b = blockIdx.x >> 4, et = blockIdx.x & 15;
  const int e0 = et*64;
  const int ob = wsi[b];
  for (int idx = tid; idx < 196*16; idx += 256){
    int p = idx >> 4, q = idx & 15;
    float4 v = *(const float4*)(enc + (size_t)ob*NP*NE + (size_t)p*NE + e0 + q*4);
    tile[p*65 + q*4+0] = v.x; tile[p*65 + q*4+1] = v.y;
    tile[p*65 + q*4+2] = v.z; tile[p*65 + q*4+3] = v.w;
  }
  __syncthreads();
  for (int idx = tid; idx < 64*52; idx += 256){
    int el = idx/52, c = idx%52;
    ushort4 o;
    int p = c*4;
    o.x = (p+0<196) ? bf16rne(tile[(p+0)*65 + el]) : (unsigned short)0;
    o.y = (p+1<196) ? bf16rne(tile[(p+1)*65 + el]) : (unsigned short)0;
    o.z = (p+2<196) ? bf16rne(tile[(p+2)*65 + el]) : (unsigned short)0;
    o.w = (p+3<196) ? bf16rne(tile[(p+3)*65 + el]) : (unsigned short)0;
    *(ushort4*)(encT + ((size_t)(b*1024 + e0 + el))*208 + c*4) = o;
  }
}

// ---------------- generic tiled fp32 GEMM (optional bf16 A / bf16 out) ----------------
// mode 2 (fc): row order m = b*31 + t; all-inactive tiles (flag wsi[32+by]==0) skip K-loop.
__global__ __launch_bounds__(256) void k_gemm(const void* __restrict__ Abase,
                                              const float* __restrict__ Bmat,
                                              const float* __restrict__ bias1,
                                              const float* __restrict__ bias2,
                                              void* __restrict__ outv,
                                              int M, int N, int K, int mode,
                                              int abf16, int obf16,
                                              const int* __restrict__ wsi,
                                              const int* __restrict__ caps){
  __shared__ float As[16*64];
  __shared__ float Bs[16*64];
  int tid = threadIdx.x;
  int n0 = blockIdx.x*64, m0 = blockIdx.y*64;
  int tx = tid&15, ty = tid>>4;
  if (mode==2 && wsi[32 + blockIdx.y] == 0){
    // whole tile inactive: write zeros, no K-loop, no B streaming
    float* outp = (float*)outv;
    #pragma unroll
    for (int i=0;i<4;i++){
      int m = m0 + ty*4 + i;
      if (m >= M) continue;
      int b = m/NT, t = m - b*NT;
      size_t obase = (size_t)b*NT*NV + (size_t)t*NV;
      #pragma unroll
      for (int j=0;j<4;j++){
        int n = n0 + tx*4 + j;
        if (n < N) outp[obase + n] = 0.0f;
      }
    }
    return;
  }
  float acc[4][4] = {};
  int r = tid>>2, kq = tid&3;
  int kk = tid>>4, nq = tid&15;
  int row = m0 + r;
  const float* arow = nullptr;
  const unsigned short* arowu = nullptr;
  if (row < M){
    if (mode==0){ int b=row/196, p=row%196; arow = (const float*)Abase + (size_t)(wsi[b]*196 + p)*NE; }
    else if (mode==1){ int t=row>>4, b=row&15; int cap = caps[wsi[b]*NL + t]; arow = (const float*)Abase + (size_t)cap*NEMB; }
    else {
      int b = row/NT, t = row - b*NT;   // fc: hhist row (t*16+b)
      if (abf16) arowu = (const unsigned short*)Abase + (size_t)(t*NB + b)*K;
      else       arow  = (const float*)Abase + (size_t)(t*NB + b)*K;
    }
  }
  int ktiles = K>>4;
  for (int kt=0; kt<ktiles; kt++){
    int k0 = kt<<4;
    float4 av = make_float4(0.f,0.f,0.f,0.f);
    if (arow) av = *(const float4*)(arow + k0 + kq*4);
    else if (arowu){
      ushort4 t = *(const ushort4*)(arowu + k0 + kq*4);
      av.x = bf2f(t.x); av.y = bf2f(t.y); av.z = bf2f(t.z); av.w = bf2f(t.w);
    }
    As[(kq*4+0)*64 + r] = av.x;
    As[(kq*4+1)*64 + r] = av.y;
    As[(kq*4+2)*64 + r] = av.z;
    As[(kq*4+3)*64 + r] = av.w;
    int ncol = n0 + nq*4;
    const float* bp = Bmat + (size_t)(k0+kk)*N + ncol;
    float4 bv;
    if (ncol+3 < N) bv = *(const float4*)bp;
    else {
      bv.x = (ncol+0<N)?bp[0]:0.f; bv.y = (ncol+1<N)?bp[1]:0.f;
      bv.z = (ncol+2<N)?bp[2]:0.f; bv.w = (ncol+3<N)?bp[3]:0.f;
    }
    *((float4*)&Bs[kk*64 + nq*4]) = bv;
    __syncthreads();
    #pragma unroll
    for (int k=0;k<16;k++){
      const float4 a = *(const float4*)(&As[k*64 + ty*4]);
      const float4 b = *(const float4*)(&Bs[k*64 + tx*4]);
      float ar[4] = {a.x,a.y,a.z,a.w};
      float br[4] = {b.x,b.y,b.z,b.w};
      #pragma unroll
      for (int i=0;i<4;i++)
        #pragma unroll
        for (int j=0;j<4;j++)
          acc[i][j] = fmaf(ar[i], br[j], acc[i][j]);
    }
    __syncthreads();
  }
  if (mode == 2){
    float* out = (float*)outv;
    #pragma unroll
    for (int i=0;i<4;i++){
      int m = m0 + ty*4 + i;
      if (m >= M) continue;
      int b = m/NT, t = m - b*NT;
      bool act = wsi[NB + b] > t;
      size_t obase = (size_t)b*NT*NV + (size_t)t*NV;
      #pragma unroll
      for (int j=0;j<4;j++){
        int n = n0 + tx*4 + j;
        if (n >= N) continue;
        out[obase + n] = act ? (acc[i][j] + bias1[n]) : 0.0f;
      }
    }
  } else {
    #pragma unroll
    for (int i=0;i<4;i++){
      int m = m0 + ty*4 + i;
      if (m >= M) continue;
      #pragma unroll
      for (int j=0;j<4;j++){
        int n = n0 + tx*4 + j;
        if (n >= N) continue;
        float v = acc[i][j] + bias1[n];
        if (bias2) v += bias2[n];
        if (obf16) ((unsigned short*)outv)[(size_t)m*N + n] = bf16rne(v);
        else       ((float*)outv)[(size_t)m*N + n] = v;
      }
    }
  }
}

// ---------------- persistent cooperative scan, 4 pods x 64 blocks x 512 threads ----------------
struct ScanParams {
  float* wsf;
  const int* wsi;
  const unsigned short* att1b;
  const unsigned short* preihb;
  const unsigned short* encT;
  const float* dec_att_W;
  const float* dec_att_b;
  const float* f_beta_W;
  const float* f_beta_b;
  const float* W_hh;
  const float* W_ih;
  const float* full_att_W;
  const float* full_att_b;
  float* out;
};

// FENCE-FREE pod-local barrier (64 blocks: 8 leaves x 8, root x 8).
__device__ __forceinline__ void podbar(unsigned* base, int bxl, unsigned target){
  __syncthreads();
  if (threadIdx.x == 0){
    unsigned* lf = base + (bxl & 7)*32;
    unsigned a = __hip_atomic_fetch_add(lf, 1u, __ATOMIC_RELEASE, __HIP_MEMORY_SCOPE_AGENT);
    if (a == 7u){
      __hip_atomic_store(lf, 0u, __ATOMIC_RELAXED, __HIP_MEMORY_SCOPE_AGENT);
      unsigned r = __hip_atomic_fetch_add(base + 256, 1u, __ATOMIC_RELEASE, __HIP_MEMORY_SCOPE_AGENT);
      if (r == 7u){
        __hip_atomic_store(base + 256, 0u, __ATOMIC_RELAXED, __HIP_MEMORY_SCOPE_AGENT);
        __hip_atomic_fetch_add(base + 288, 1u, __ATOMIC_RELEASE, __HIP_MEMORY_SCOPE_AGENT);
      }
    }
    while ((int)(__hip_atomic_load(base + 288, __ATOMIC_RELAXED, __HIP_MEMORY_SCOPE_AGENT) - target) < 0)
      __builtin_amdgcn_s_sleep(1);
  }
  __syncthreads();
  __asm__ volatile("" ::: "memory");
}

__global__ __launch_bounds__(512, 2) void k_scan(ScanParams P){
  extern __shared__ __align__(16) unsigned char smem[];
  unsigned short* att1p = (unsigned short*)smem;              // [13][1024] bf16
  unsigned short* encp  = (unsigned short*)(smem + 26624);    // [64][210] bf16
  float* uni     = (float*)(smem + 53504);                    // hs (4x640) / ags (4x1280) union
  float* scratch = (float*)(smem + 73984);                    // 2176 f32

  const int tid = threadIdx.x;
  const int bx = blockIdx.x;           // [0,256)
  const int pod = bx >> 6;             // 4 pods
  const int bxl = bx & 63;             // pod-local block id
  const int B0 = pod*4;                // pod owns batches [B0, B0+4)
  const int lane = tid & 63;
  const int wid = tid >> 6;            // [0,8)

  float* M1     = P.wsf + WS_M1;
  float* hws    = P.wsf + WS_H;
  float* cws    = P.wsf + WS_C;
  float* scores = P.wsf + WS_SCORES;
  float* aweg   = P.wsf + WS_AWEG;
  unsigned short* hhist_us = (unsigned short*)(P.wsf + WS_HHIST);
  unsigned* bbase = (unsigned*)(P.wsf) + WS_LEAF + pod*320;
  const int* declen = P.wsi + NB;
  unsigned target = 0;

  const float* Wih2 = P.W_ih + (size_t)512*NG;
  const float fab = P.full_att_b[0];

  // ---- Phase A ownership: pod block bxl owns M1 cols [bxl*64, bxl*64+64), 4 batches.
  const int kcA = tid >> 6, cA = tid & 63;
  int modeA; const float* WAp; int jbA, ldwA;
  if (bxl < 16)      { WAp = P.dec_att_W; jbA = bxl*64;       ldwA = 1024; modeA = 0; }
  else if (bxl < 32) { WAp = P.f_beta_W;  jbA = (bxl-16)*64;  ldwA = 1024; modeA = 1; }
  else               { WAp = P.W_hh;      jbA = (bxl-32)*64;  ldwA = 2048; modeA = 2; }
  float wA[64];
  #pragma unroll
  for (int i=0;i<64;i++) wA[i] = WAp[(size_t)(kcA*64+i)*ldwA + jbA + cA];

  // ---- Phase D ownership: pod block bxl owns d-slice [bxl*8, bxl*8+8) x 4 gates, 4 batches.
  const int kcD = tid >> 5, cD = tid & 31;
  const int jD = (cD>>3)*512 + bxl*8 + (cD&7);
  float wD[64];
  #pragma unroll
  for (int i=0;i<64;i++) wD[i] = Wih2[(size_t)(kcD*64+i)*NG + jD];

  // persistent full_att_W fragment in registers (lane-sliced)
  float faw[16];
  {
    const float* fw = P.full_att_W + lane*8;
    #pragma unroll
    for (int i=0;i<2;i++){
      float4 x = *(const float4*)(fw + i*512);
      float4 y = *(const float4*)(fw + i*512 + 4);
      faw[i*8+0]=x.x; faw[i*8+1]=x.y; faw[i*8+2]=x.z; faw[i*8+3]=x.w;
      faw[i*8+4]=y.x; faw[i*8+5]=y.y; faw[i*8+6]=y.z; faw[i*8+7]=y.w;
    }
  }

  // ---- one-time preload of persistent LDS (block-private bf16 slices) ----
  {
    const int b = bx >> 4, sub = bx & 15;
    const int p0 = sub*13;
    const int cnt = (sub==15) ? 1 : 13;
    const uint4* s4 = (const uint4*)(P.att1b + ((size_t)(b*196 + p0))*1024);
    uint4* d4 = (uint4*)att1p;
    for (int i = tid; i < cnt*128; i += 512) d4[i] = s4[i];
    const unsigned* es = (const unsigned*)P.encT + (((size_t)(b*1024 + sub*64))*208 >> 1);
    unsigned* ed = (unsigned*)encp;
    for (int i = tid; i < 64*104; i += 512){
      int el = i/104, c = i%104;
      ed[el*105 + c] = es[el*104 + c];
    }
  }
  __syncthreads();

  float pa[4];

  for (int tt=0; tt<NT; tt++){
    // ---- pod early-exit: all batches in pod done (declen sorted desc within pod)
    if (declen[B0] <= tt){
      if ((bxl & 15) == 0){
        int b = B0 + (bxl >> 4);
        for (int t2 = tt; t2 < NT; t2++)
          for (int p = tid; p < NP; p += 512)
            P.out[OFF_ALPHAS + (size_t)b*NT*NP + (size_t)t2*NP + p] = 0.f;
      }
      break;
    }

    // ---- preamble: load h(tt) for pod's 4 batches into LDS (20-word padded chunks)
    #pragma unroll
    for (int i=0;i<2;i++){
      int idx = tid + i*512;           // float2 units [0,1024)
      int b = idx >> 8, dp = (idx & 255)*2;
      float2 v = cload2(hws + (size_t)(B0+b)*ND + dp);
      int a = b*640 + (dp>>4)*20 + (dp&15);
      uni[a]   = v.x;
      uni[a+1] = v.y;
    }
    __syncthreads();

    // ---- Phase A: M1[B0+b][bxl*64+c] ; weights in regs, split-K (8 waves) LDS reduce
    {
      #pragma unroll
      for (int b=0;b<4;b++){
        float s = 0.f;
        #pragma unroll
        for (int cq=0;cq<4;cq++){
          const float4* hp = (const float4*)(uni + b*640 + kcA*80 + cq*20);
          float4 a0 = hp[0], a1 = hp[1], a2 = hp[2], a3 = hp[3];
          s = fmaf(a0.x,wA[cq*16+0],s);  s = fmaf(a0.y,wA[cq*16+1],s);  s = fmaf(a0.z,wA[cq*16+2],s);  s = fmaf(a0.w,wA[cq*16+3],s);
          s = fmaf(a1.x,wA[cq*16+4],s);  s = fmaf(a1.y,wA[cq*16+5],s);  s = fmaf(a1.z,wA[cq*16+6],s);  s = fmaf(a1.w,wA[cq*16+7],s);
          s = fmaf(a2.x,wA[cq*16+8],s);  s = fmaf(a2.y,wA[cq*16+9],s);  s = fmaf(a2.z,wA[cq*16+10],s); s = fmaf(a2.w,wA[cq*16+11],s);
          s = fmaf(a3.x,wA[cq*16+12],s); s = fmaf(a3.y,wA[cq*16+13],s); s = fmaf(a3.z,wA[cq*16+14],s); s = fmaf(a3.w,wA[cq*16+15],s);
        }
        pa[b] = s;
      }
      #pragma unroll
      for (int b=0;b<4;b++) scratch[kcA*256 + b*64 + cA] = pa[b];
      __syncthreads();
      if (tid < 256){
        float s = 0.f;
        #pragma unroll
        for (int w=0;w<8;w++) s += scratch[w*256 + tid];
        int b = tid >> 6, c = tid & 63;
        int jout = bxl*64 + c;
        float v;
        if (modeA==0)      v = s + P.dec_att_b[jout];
        else if (modeA==1) v = sigf(s + P.f_beta_b[jout-1024]);
        else               v = s;
        cstore(&M1[(size_t)(B0+b)*4096 + jout], v);
      }
    }
    podbar(bbase, bxl, ++target);

    // ---- Phase D operand prefetch (both ready after barrier 1; used after barrier 3)
    float gpre = 0.f;
    if (tid < 128){
      const int cQ = tid & 31, bQ = tid >> 5;
      const int jQ = (cQ>>3)*512 + bxl*8 + (cQ&7);
      const int BQ = B0 + bQ;
      gpre = cload(&M1[(size_t)BQ*4096 + 2048 + jQ]) + bf2f(P.preihb[(size_t)(tt*NB + BQ)*NG + jQ]);
    }

    // ---- Phase B: scores = relu(att1b + att2).faw + fab  (att1 rows from LDS)
    {
      const int b = B0 + (bxl >> 4), sidx = bxl & 15;
      if (declen[b] > tt){
        float a2r[16];
        {
          const float* m1b = M1 + (size_t)b*4096 + lane*8;
          #pragma unroll
          for (int i=0;i<2;i++){
            #pragma unroll
            for (int q=0;q<4;q++){
              float2 t = cload2(m1b + i*512 + q*2);
              a2r[i*8+q*2]   = t.x;
              a2r[i*8+q*2+1] = t.y;
            }
          }
        }
        const int p0 = sidx*13;
        const int cnt = (sidx==15) ? 1 : 13;
        for (int rr = wid; rr < cnt; rr += 8){
          int p = p0 + rr;
          const unsigned short* a1 = att1p + (size_t)rr*1024;
          float s = 0.f;
          #pragma unroll
          for (int i=0;i<2;i++){
            uint4 u = *(const uint4*)(a1 + i*512 + lane*8);
            float f0,f1,v;
            u2f2(u.x,f0,f1);
            v = f0 + a2r[i*8+0]; v = v>0.f?v:0.f; s = fmaf(v, faw[i*8+0], s);
            v = f1 + a2r[i*8+1]; v = v>0.f?v:0.f; s = fmaf(v, faw[i*8+1], s);
            u2f2(u.y,f0,f1);
            v = f0 + a2r[i*8+2]; v = v>0.f?v:0.f; s = fmaf(v, faw[i*8+2], s);
            v = f1 + a2r[i*8+3]; v = v>0.f?v:0.f; s = fmaf(v, faw[i*8+3], s);
            u2f2(u.z,f0,f1);
            v = f0 + a2r[i*8+4]; v = v>0.f?v:0.f; s = fmaf(v, faw[i*8+4], s);
            v = f1 + a2r[i*8+5]; v = v>0.f?v:0.f; s = fmaf(v, faw[i*8+5], s);
            u2f2(u.w,f0,f1);
            v = f0 + a2r[i*8+6]; v = v>0.f?v:0.f; s = fmaf(v, faw[i*8+6], s);
            v = f1 + a2r[i*8+7]; v = v>0.f?v:0.f; s = fmaf(v, faw[i*8+7], s);
          }
          #pragma unroll
          for (int off=32; off; off>>=1) s += __shfl_down(s, off, 64);
          if (lane == 0) cstore(&scores[b*256 + p], s + fab);
        }
      }
    }
    podbar(bbase, bxl, ++target);

    // ---- Phase C: redundant softmax (wave-shuffle) + awe chunk (64 e) from LDS encp
    {
      const int b = B0 + (bxl >> 4), ch = bxl & 15;
      if (declen[b] <= tt){
        if (ch == 0 && tid < 196)
          P.out[OFF_ALPHAS + (size_t)b*NT*NP + (size_t)tt*NP + tid] = 0.f;
      } else {
        float* sc   = scratch;            // 208 alphas (zero-padded)
        float* wred = scratch + 208;      // 16: wave max[8] | wave sum[8]
        float* redp = scratch + 464;      // 8*68
        float v = (tid < 196) ? cload(&scores[b*256 + tid]) : -1e30f;
        float mw = v;
        #pragma unroll
        for (int off=32; off; off>>=1) mw = fmaxf(mw, __shfl_xor(mw, off, 64));
        if (lane == 0) wred[wid] = mw;
        __syncthreads();
        float mx = wred[0];
        #pragma unroll
        for (int w=1;w<8;w++) mx = fmaxf(mx, wred[w]);
        float ex = (tid < 196) ? expf(v - mx) : 0.f;
        float sm = ex;
        #pragma unroll
        for (int off=32; off; off>>=1) sm += __shfl_xor(sm, off, 64);
        if (lane == 0) wred[8+wid] = sm;
        __syncthreads();
        float tot = wred[8];
        #pragma unroll
        for (int w=1;w<8;w++) tot += wred[8+w];
        const float inv = 1.f / tot;
        if (tid < 208) sc[tid] = (tid < 196) ? ex*inv : 0.f;
        __syncthreads();
        const int el = tid & 63, pp = tid >> 6;
        const unsigned* erowL = ((const unsigned*)encp) + el*105 + pp*13;
        float part = 0.f;
        #pragma unroll
        for (int i=0;i<13;i++){
          unsigned u = erowL[i];
          float f0,f1; u2f2(u,f0,f1);
          part = fmaf(f0, sc[pp*26 + 2*i],     part);
          part = fmaf(f1, sc[pp*26 + 2*i + 1], part);
        }
        redp[pp*68 + el] = part;
        __syncthreads();
        if (tid < 64){
          float aw = 0.f;
          #pragma unroll
          for (int q=0;q<8;q++) aw += redp[q*68 + tid];
          int e2 = ch*64 + tid;
          cstore(&aweg[b*1024 + e2], cload(&M1[(size_t)b*4096 + 1024 + e2]) + aw);
        }
        if (ch == 0 && tid < 196){
          P.out[OFF_ALPHAS + (size_t)b*NT*NP + (size_t)tt*NP + tid] = sc[tid];
        }
        __syncthreads();
      }
    }
    podbar(bbase, bxl, ++target);

    // ---- Phase D: gates for d-slice [bxl*8, bxl*8+8) x 4 gates, pod's 4 batches
    {
      #pragma unroll
      for (int i=0;i<4;i++){
        int idx = tid + i*512;          // float2 units [0,2048)
        int b = idx >> 9, ep = (idx & 511)*2;
        float2 v = cload2(aweg + (size_t)(B0+b)*1024 + ep);
        int a = b*1280 + (ep>>4)*20 + (ep&15);
        uni[a]   = v.x;
        uni[a+1] = v.y;
      }
      __syncthreads();
      #pragma unroll
      for (int b=0;b<4;b++){
        float s = 0.f;
        #pragma unroll
        for (int cq=0;cq<4;cq++){
          const float4* ap = (const float4*)(uni + b*1280 + kcD*80 + cq*20);
          float4 a0 = ap[0], a1 = ap[1], a2 = ap[2], a3 = ap[3];
          s = fmaf(a0.x,wD[cq*16+0],s);  s = fmaf(a0.y,wD[cq*16+1],s);  s = fmaf(a0.z,wD[cq*16+2],s);  s = fmaf(a0.w,wD[cq*16+3],s);
          s = fmaf(a1.x,wD[cq*16+4],s);  s = fmaf(a1.y,wD[cq*16+5],s);  s = fmaf(a1.z,wD[cq*16+6],s);  s = fmaf(a1.w,wD[cq*16+7],s);
          s = fmaf(a2.x,wD[cq*16+8],s);  s = fmaf(a2.y,wD[cq*16+9],s);  s = fmaf(a2.z,wD[cq*16+10],s); s = fmaf(a2.w,wD[cq*16+11],s);
          s = fmaf(a3.x,wD[cq*16+12],s); s = fmaf(a3.y,wD[cq*16+13],s); s = fmaf(a3.z,wD[cq*16+14],s); s = fmaf(a3.w,wD[cq*16+15],s);
        }
        pa[b] = s;
      }
      #pragma unroll
      for (int b=0;b<4;b++) scratch[kcD*128 + b*32 + cD] = pa[b];
      __syncthreads();
      float* gl = scratch + 2048;       // 128
      if (tid < 128){
        float s = 0.f;
        #pragma unroll
        for (int w=0;w<16;w++) s += scratch[w*128 + tid];
        int c = tid & 31, b = tid >> 5;
        float gv = s + gpre;            // preihb + M1 gates prefetched after barrier 1
        gl[b*32 + c] = gv;              // c = g*8+dq
      }
      __syncthreads();
      if (tid < 32){
        const int b = tid >> 3, dq = tid & 7;
        const int B = B0 + b, d = bxl*8 + dq;
        const float gI = gl[b*32 + 0  + dq];
        const float gF = gl[b*32 + 8  + dq];
        const float gG = gl[b*32 + 16 + dq];
        const float gO = gl[b*32 + 24 + dq];
        const float co = cws[(size_t)B*ND + d];  // block-private (same owner every step)
        const float cn = sigf(gF)*co + sigf(gI)*tanhf(gG);
        const float hn = sigf(gO)*tanhf(cn);
        hhist_us[((size_t)tt*NB + B)*ND + d] = bf16rne(hn);
        if (declen[B] > tt){
          cstore(&hws[(size_t)B*ND + d], hn);    // broadcast h coherently
          cws[(size_t)B*ND + d] = cn;
        }
      }
      __syncthreads();
    }
    podbar(bbase, bxl, ++target);
  }
}

extern "C" void kernel_launch(void* const* d_in, const int* in_sizes, int n_in,
                              void* d_out, int out_size, void* d_ws, size_t ws_size,
                              hipStream_t stream) {
  const float* encoder_out = (const float*)d_in[0];
  const float* enc_att_W   = (const float*)d_in[1];
  const float* enc_att_b   = (const float*)d_in[2];
  const float* dec_att_W   = (const float*)d_in[3];
  const float* dec_att_b   = (const float*)d_in[4];
  const float* full_att_W  = (const float*)d_in[5];
  const float* full_att_b  = (const float*)d_in[6];
  const float* emb         = (const float*)d_in[7];
  const float* W_ih        = (const float*)d_in[8];
  const float* b_ih        = (const float*)d_in[9];
  const float* W_hh        = (const float*)d_in[10];
  const float* b_hh        = (const float*)d_in[11];
  const float* init_h_W    = (const float*)d_in[12];
  const float* init_h_b    = (const float*)d_in[13];
  const float* init_c_W    = (const float*)d_in[14];
  const float* init_c_b    = (const float*)d_in[15];
  const float* f_beta_W    = (const float*)d_in[16];
  const float* f_beta_b    = (const float*)d_in[17];
  const float* fc_W        = (const float*)d_in[18];
  const float* fc_b        = (const float*)d_in[19];
  const int*   caps        = (const int*)d_in[20];
  const int*   caplen      = (const int*)d_in[21];
  (void)in_sizes; (void)n_in; (void)out_size; (void)ws_size;

  float* out = (float*)d_out;
  float* wsf = (float*)d_ws;
  int*   wsi = (int*)d_ws;
  unsigned short* att1b  = (unsigned short*)(out + OFF_ATT1B);
  unsigned short* preihb = (unsigned short*)(out + OFF_PREIHB);
  unsigned short* encT   = (unsigned short*)(out + OFF_ENCT);

  hipFuncSetAttribute((const void*)k_scan, hipFuncAttributeMaxDynamicSharedMemorySize, SMEM_BYTES);

  hipLaunchKernelGGL(k_sort, dim3(1), dim3(64), 0, stream, caplen, caps, wsi, out);
  hipLaunchKernelGGL(k_mean, dim3(64), dim3(256), 0, stream, encoder_out, wsi, wsf);
  hipLaunchKernelGGL(k_init, dim3(64), dim3(256), 0, stream, init_h_W, init_h_b, init_c_W, init_c_b, wsf);
  hipLaunchKernelGGL(k_trans, dim3(256), dim3(256), 0, stream, encoder_out, wsi, encT);
  // att1 (bf16 out) : M=3136, N=1024, K=1024
  hipLaunchKernelGGL(k_gemm, dim3(16,49), dim3(256), 0, stream,
                     (const void*)encoder_out, enc_att_W, enc_att_b, (const float*)nullptr,
                     (void*)att1b, 3136, 1024, 1024, 0, 0, 1, wsi, caps);
  // pre_ih (bf16 out) : M=496, N=2048, K=512
  hipLaunchKernelGGL(k_gemm, dim3(32,8), dim3(256), 0, stream,
                     (const void*)emb, W_ih, b_ih, b_hh,
                     (void*)preihb, 496, 2048, 512, 1, 0, 1, wsi, caps);

  ScanParams sp;
  sp.wsf = wsf; sp.wsi = wsi;
  sp.att1b = att1b; sp.preihb = preihb; sp.encT = encT;
  sp.dec_att_W = dec_att_W; sp.dec_att_b = dec_att_b;
  sp.f_beta_W = f_beta_W; sp.f_beta_b = f_beta_b;
  sp.W_hh = W_hh; sp.W_ih = W_ih;
  sp.full_att_W = full_att_W; sp.full_att_b = full_att_b;
  sp.out = out;
  void* args[] = { &sp };
  hipLaunchCooperativeKernel((void*)k_scan, dim3(NBLK), dim3(512), args, SMEM_BYTES, stream);

  // predictions = hhist(bf16) @ fc_W + fc_b (masked, row order b*31+t, dead tiles skip)
  hipLaunchKernelGGL(k_gemm, dim3(157,8), dim3(256), 0, stream,
                     (const void*)(wsf + WS_HHIST), fc_W, fc_b, (const float*)nullptr,
                     (void*)out, 496, 10000, 512, 2, 1, 0, wsi, caps);
}